// Round 5
// baseline (111.358 us; speedup 1.0000x reference)
//
#include <hip/hip_runtime.h>
#include <hip/hip_bf16.h>

// KANLinear as bf16 MFMA GEMM, fully materialized A:
//   y = A @ W'^T + skip_b
//   A  (2048 x 4352) bf16, PRECOMPUTED in ws: per dim d, 16 hat weights
//       max(0,1-|t-k|) with t=(clamp(x)+1)*7.5 (cols 0..4095), then clamp(x) (skip).
//   W' (256  x 4352) bf16: row o = [values[o,:,:] flat | skip_w[o,:]].
// GEMM: 64x64x64 tiles, NSPLIT=8 split-K, register-buffered double-buffered LDS
// pipeline (one barrier/step, loads overlap compute). fp32 partials -> reduce.

namespace {
constexpr int Bsz  = 2048;
constexpr int Din  = 256;
constexpr int Dout = 256;
constexpr int Kn   = 16;
constexpr int KKNOT = Din * Kn;        // 4096
constexpr int Ksp   = KKNOT + Din;     // 4352
constexpr float INV_H = 7.5f;          // 1 / (2/15)
constexpr float Hgrid = 2.0f / 15.0f;

constexpr int BM = 64, BN = 64, BK = 64;
constexpr int TOTSTEP = Ksp / BK;      // 68
constexpr int NSPLIT  = 8;             // ragged: 9,9,9,9,9,9,9,5 steps
constexpr int SPS     = 9;             // steps per split (last split shorter)
constexpr int MT = Bsz / BM;           // 32
constexpr int NT = Dout / BN;          // 4
}

typedef __attribute__((ext_vector_type(8))) short shortx8;   // 8 bf16 = 4 VGPR
typedef __attribute__((ext_vector_type(4))) float floatx4;   // MFMA acc

__device__ __forceinline__ unsigned int f2bf(float f) {
  __hip_bfloat16 h = __float2bfloat16(f);
  return (unsigned int)*reinterpret_cast<unsigned short*>(&h);
}

// --- Prep: build A (bf16 hats + skip) and W' (bf16 cast). Grid 2048x256. ---
__global__ __launch_bounds__(256) void kan_prep(
    const float* __restrict__ x, const float* __restrict__ values,
    const float* __restrict__ skip_w, unsigned short* __restrict__ Abf,
    unsigned short* __restrict__ Wt) {
  const int idx = blockIdx.x * 256 + threadIdx.x;   // = b*256 + d, exactly 524288
  const int b = idx >> 8, d = idx & 255;

  // A knot block: 16 hat weights for (b,d).
  const float xr = x[idx];
  const float xc = fminf(1.f, fmaxf(-1.f, xr));
  const float t  = (xc + 1.f) * INV_H;
  unsigned int u[8];
  #pragma unroll
  for (int i = 0; i < 8; ++i) {
    const float a0 = fmaxf(0.f, 1.f - fabsf(t - (float)(2 * i)));
    const float a1 = fmaxf(0.f, 1.f - fabsf(t - (float)(2 * i + 1)));
    u[i] = f2bf(a0) | (f2bf(a1) << 16);
  }
  unsigned short* arow = Abf + (size_t)b * Ksp;
  uint4* dst = (uint4*)(arow + d * 16);
  dst[0] = make_uint4(u[0], u[1], u[2], u[3]);
  dst[1] = make_uint4(u[4], u[5], u[6], u[7]);
  // A skip column.
  arow[KKNOT + d] = (unsigned short)f2bf(xc);

  // W' build (first 139264 threads): 8 elems each, coalesced.
  if (idx < (KKNOT * Dout + Din * Dout) / 8) {
    const float* src;
    unsigned short* wdst;
    if (idx < KKNOT * Dout / 8) {
      const int o = idx >> 9, i = idx & 511;
      src = values + (size_t)idx * 8;
      wdst = Wt + (size_t)o * Ksp + i * 8;
    } else {
      const int c2 = idx - KKNOT * Dout / 8;
      const int o = c2 >> 5, i = c2 & 31;
      src = skip_w + (size_t)c2 * 8;
      wdst = Wt + (size_t)o * Ksp + KKNOT + i * 8;
    }
    const float4 v0 = *(const float4*)src;
    const float4 v1 = *(const float4*)(src + 4);
    *(uint4*)wdst = make_uint4(f2bf(v0.x) | (f2bf(v0.y) << 16),
                               f2bf(v0.z) | (f2bf(v0.w) << 16),
                               f2bf(v1.x) | (f2bf(v1.y) << 16),
                               f2bf(v1.z) | (f2bf(v1.w) << 16));
  }
}

// --- GEMM: grid = 32 mt x 4 nt x 8 splits = 1024 blocks (4/CU), 256 threads. ---
// Register-buffered pipeline: global->VGPR loads issued one step ahead;
// ds_write (which waits vmcnt) lands after a full compute phase. 1 barrier/step.
__global__ __launch_bounds__(256) void kan_gemm(
    const unsigned short* __restrict__ Abf, const unsigned short* __restrict__ Wt,
    float* __restrict__ part) {
  __shared__ __align__(16) unsigned short As[2][BM][BK];   // 2 x 8 KB
  __shared__ __align__(16) unsigned short Bs[2][BN][BK];   // 2 x 8 KB

  const int tid = threadIdx.x;
  const int ks  = blockIdx.x % NSPLIT;
  const int nt  = (blockIdx.x / NSPLIT) % NT;
  const int mt  = blockIdx.x / (NSPLIT * NT);
  const int m0 = mt * BM, n0 = nt * BN;
  const int g0 = ks * SPS;
  const int g1 = (g0 + SPS < TOTSTEP) ? g0 + SPS : TOTSTEP;

  // Staging map: chunks cc = tid (p0) and tid+256 (p1) for each of A and B.
  // chunk cc -> (row = cc>>3, slot = cc&7); global source chunk kc = slot^(row&7)
  // (XOR swizzle so frag reads are conflict-free); LDS dest is linear at cc*16B.
  const unsigned short* ga[4];
  #pragma unroll
  for (int p = 0; p < 2; ++p) {
    const int cc = tid + p * 256;
    const int row = cc >> 3;
    const int kc = (cc & 7) ^ (row & 7);
    ga[p]     = Abf + (size_t)(m0 + row) * Ksp + kc * 8;
    ga[p + 2] = Wt  + (size_t)(n0 + row) * Ksp + kc * 8;
  }

  const int wave = tid >> 6, lane = tid & 63;
  const int wm = (wave & 1) * 32, wn = (wave >> 1) * 32;
  const int lrow = lane & 15, lq = lane >> 4;

  floatx4 acc[2][2] = {};
  uint4 ra[4];

  // Prolog: load step g0 into regs.
  #pragma unroll
  for (int p = 0; p < 4; ++p) ra[p] = *(const uint4*)(ga[p] + (size_t)g0 * 64);

  int buf = 0;
  for (int g = g0; g < g1; ++g) {
    // Drain staged regs to LDS (vmcnt wait here, hidden by previous compute).
    *(uint4*)(&As[buf][0][0] + (size_t)tid * 8)         = ra[0];
    *(uint4*)(&As[buf][0][0] + (size_t)(tid + 256) * 8) = ra[1];
    *(uint4*)(&Bs[buf][0][0] + (size_t)tid * 8)         = ra[2];
    *(uint4*)(&Bs[buf][0][0] + (size_t)(tid + 256) * 8) = ra[3];
    __syncthreads();

    // Issue next step's loads (no wait until next iteration's ds_write).
    if (g + 1 < g1) {
      #pragma unroll
      for (int p = 0; p < 4; ++p) ra[p] = *(const uint4*)(ga[p] + (size_t)(g + 1) * 64);
    }

    // Fragments + MFMA from current buffer.
    shortx8 af[2][2], bfr[2][2];
    #pragma unroll
    for (int i = 0; i < 2; ++i) {
      const int r = wm + 16 * i + lrow;
      #pragma unroll
      for (int kk = 0; kk < 2; ++kk) {
        const int slot = (kk * 4 + lq) ^ (r & 7);
        af[i][kk] = *(const shortx8*)(&As[buf][0][0] + r * 64 + slot * 8);
      }
    }
    #pragma unroll
    for (int j = 0; j < 2; ++j) {
      const int r = wn + 16 * j + lrow;
      #pragma unroll
      for (int kk = 0; kk < 2; ++kk) {
        const int slot = (kk * 4 + lq) ^ (r & 7);
        bfr[j][kk] = *(const shortx8*)(&Bs[buf][0][0] + r * 64 + slot * 8);
      }
    }
    #pragma unroll
    for (int kk = 0; kk < 2; ++kk)
      #pragma unroll
      for (int i = 0; i < 2; ++i)
        #pragma unroll
        for (int j = 0; j < 2; ++j)
          acc[i][j] = __builtin_amdgcn_mfma_f32_16x16x32_bf16(af[i][kk], bfr[j][kk], acc[i][j], 0, 0, 0);

    buf ^= 1;
  }

  // Epilogue: plain stores to this split's partial. C/D: col=lane&15, row=quad*4+reg.
  float* P = part + (size_t)ks * Bsz * Dout;
  #pragma unroll
  for (int i = 0; i < 2; ++i) {
    const int grow = m0 + wm + 16 * i + lq * 4;
    #pragma unroll
    for (int j = 0; j < 2; ++j) {
      const int gcol = n0 + wn + 16 * j + lrow;
      #pragma unroll
      for (int r = 0; r < 4; ++r)
        P[(size_t)(grow + r) * Dout + gcol] = acc[i][j][r];
    }
  }
}

// --- Reduce 8 partials + bias -> out. float4 per thread. ---
__global__ __launch_bounds__(256) void kan_reduce(
    const float* __restrict__ part, const float* __restrict__ skip_b,
    float* __restrict__ out) {
  const int i = blockIdx.x * 256 + threadIdx.x;   // float4 index
  const int base = i * 4;
  const int o = base & (Dout - 1);
  float4 a = *(const float4*)(skip_b + o);
  #pragma unroll
  for (int s = 0; s < NSPLIT; ++s) {
    const float4 p = *(const float4*)(part + (size_t)s * Bsz * Dout + base);
    a.x += p.x; a.y += p.y; a.z += p.z; a.w += p.w;
  }
  *(float4*)(out + base) = a;
}

// ---------------- Fallback (round-1 structure, needs 4.4 MB ws) ----------------
__device__ __forceinline__ void knot_interp(float xraw, float& xv, float& w, int& l) {
  xv = fminf(1.0f, fmaxf(-1.0f, xraw));
  float t = (xv + 1.0f) * INV_H;
  l = (int)ceilf(t) - 1;
  l = l < 0 ? 0 : (l > Kn - 2 ? Kn - 2 : l);
  float g0 = -1.0f + Hgrid * (float)l;
  w = (xv - g0) * INV_H;
}

__global__ __launch_bounds__(256) void prep_transpose(
    const float* __restrict__ values, const float* __restrict__ skip_w,
    float* __restrict__ vt, float* __restrict__ swt) {
  int idx = blockIdx.x * blockDim.x + threadIdx.x;
  if (idx < Din * Kn * Dout) {
    int k = idx & (Kn - 1);
    int d = (idx >> 4) & (Din - 1);
    int o = idx >> 12;
    vt[(d * Kn + k) * Dout + o] = values[idx];
  }
  if (idx < Dout * Din) {
    int d = idx & (Din - 1);
    int o = idx >> 8;
    swt[d * Dout + o] = skip_w[idx];
  }
}

__global__ __launch_bounds__(256) void kan_main(
    const float* __restrict__ x, const float* __restrict__ vt,
    const float* __restrict__ swt, const float* __restrict__ skip_b,
    float* __restrict__ out) {
  __shared__ float s_w[4][Din];
  __shared__ float s_x[4][Din];
  __shared__ int   s_l[4][Din];
  const int tid = threadIdx.x;
  const int b0  = blockIdx.x * 4;
  for (int i = tid; i < 4 * Din; i += 256) {
    int bb = i >> 8;
    int d  = i & (Din - 1);
    float xv, w; int l;
    knot_interp(x[(b0 + bb) * Din + d], xv, w, l);
    s_w[bb][d] = w; s_x[bb][d] = xv; s_l[bb][d] = l;
  }
  __syncthreads();
  const int g = tid >> 6, lane = tid & 63;
  const int o = lane << 2, b = b0 + g;
  float4 acc = make_float4(0.f, 0.f, 0.f, 0.f);
  for (int d = 0; d < Din; ++d) {
    const float w = s_w[g][d], xv = s_x[g][d];
    const int l = s_l[g][d];
    const float* base = vt + (d * Kn + l) * Dout + o;
    const float4 vl = *(const float4*)(base);
    const float4 vr = *(const float4*)(base + Dout);
    const float4 sw = *(const float4*)(swt + d * Dout + o);
    acc.x = fmaf(xv, sw.x, fmaf(w, vr.x - vl.x, acc.x + vl.x));
    acc.y = fmaf(xv, sw.y, fmaf(w, vr.y - vl.y, acc.y + vl.y));
    acc.z = fmaf(xv, sw.z, fmaf(w, vr.z - vl.z, acc.z + vl.z));
    acc.w = fmaf(xv, sw.w, fmaf(w, vr.w - vl.w, acc.w + vl.w));
  }
  const float4 bias = *(const float4*)(skip_b + o);
  acc.x += bias.x; acc.y += bias.y; acc.z += bias.z; acc.w += bias.w;
  *(float4*)(out + (size_t)b * Dout + o) = acc;
}

extern "C" void kernel_launch(void* const* d_in, const int* in_sizes, int n_in,
                              void* d_out, int out_size, void* d_ws, size_t ws_size,
                              hipStream_t stream) {
  (void)in_sizes; (void)n_in; (void)out_size;
  const float* x      = (const float*)d_in[0];
  const float* values = (const float*)d_in[1];
  const float* skip_w = (const float*)d_in[2];
  const float* skip_b = (const float*)d_in[3];
  float* out = (float*)d_out;

  const size_t a_bytes    = (size_t)Bsz * Ksp * sizeof(unsigned short);      // 17.8 MB
  const size_t wt_bytes   = (size_t)Dout * Ksp * sizeof(unsigned short);     // 2.23 MB
  const size_t part_bytes = (size_t)NSPLIT * Bsz * Dout * sizeof(float);     // 16.8 MB
  const size_t need_gemm  = a_bytes + wt_bytes + part_bytes;
  const size_t need_fb    = (size_t)(Din * Kn * Dout + Din * Dout) * sizeof(float);

  if (ws_size >= need_gemm) {
    unsigned short* Abf = (unsigned short*)d_ws;
    unsigned short* Wt  = (unsigned short*)((char*)d_ws + a_bytes);
    float* part = (float*)((char*)d_ws + a_bytes + wt_bytes);
    kan_prep<<<Bsz * Din / 256, 256, 0, stream>>>(x, values, skip_w, Abf, Wt);
    kan_gemm<<<MT * NT * NSPLIT, 256, 0, stream>>>(Abf, Wt, part);
    kan_reduce<<<Bsz * Dout / 4 / 256, 256, 0, stream>>>(part, skip_b, out);
  } else if (ws_size >= need_fb) {
    float* vt  = (float*)d_ws;
    float* swt = vt + Din * Kn * Dout;
    prep_transpose<<<(Din * Kn * Dout + 255) / 256, 256, 0, stream>>>(values, skip_w, vt, swt);
    kan_main<<<Bsz / 4, 256, 0, stream>>>(x, vt, swt, skip_b, out);
  }
}

// Round 6
// 102.193 us; speedup vs baseline: 1.0897x; 1.0897x over previous
//
#include <hip/hip_runtime.h>
#include <hip/hip_bf16.h>

// KANLinear as fragment-direct bf16 MFMA GEMM (no LDS, no barriers):
//   y = A @ W'^T + skip_b
//   A (2048 x 4352) VIRTUAL: per dim d, 16 hat weights max(0,1-|t-k|),
//     t=(clamp(x)+1)*7.5 (cols 0..4095), then 256 cols clamp(x) (skip).
//     A-fragments are synthesized in registers per MFMA.
//   W' (256 x 4352) bf16, PRE-PERMUTED into MFMA B-fragment order in ws:
//     chunk(kb,og,q,n) = W'[og*16+n][kb*32+q*8 .. +8], so a wave loads a
//     16x32 B-frag as one coalesced 16B/lane dwordx4 (lane = q*16+n).
// K-split 8 -> fp32 partials -> reduce(+bias).

namespace {
constexpr int Bsz  = 2048;
constexpr int Din  = 256;
constexpr int Dout = 256;
constexpr int Kn   = 16;
constexpr int KKNOT = Din * Kn;        // 4096
constexpr int Ksp   = KKNOT + Din;     // 4352
constexpr int KB    = Ksp / 32;        // 136 k-blocks of 32
constexpr float INV_H = 7.5f;          // 1 / (2/15)
constexpr float Hgrid = 2.0f / 15.0f;

constexpr int NSPLIT = 8;              // 17 kblocks per split
constexpr int SPS    = KB / NSPLIT;    // 17
}

typedef __attribute__((ext_vector_type(8))) short shortx8;   // 8 bf16 = 4 VGPR
typedef __attribute__((ext_vector_type(4))) float floatx4;   // MFMA acc

__device__ __forceinline__ unsigned int f2bf(float f) {
  __hip_bfloat16 h = __float2bfloat16(f);
  return (unsigned int)*reinterpret_cast<unsigned short*>(&h);
}
__device__ __forceinline__ float clamp1(float v) {
  return fminf(1.f, fmaxf(-1.f, v));
}

union FragCvt { uint4 u; shortx8 s; };

// --- Prep: permute W' into B-fragment order. 544 blocks x 256. ---
// tid -> (q = tid&3, n = (tid>>2)&15, og = (tid>>6)&15, kb = tid>>10).
// Reads 8 consecutive floats (coalesced 128B per 4 lanes); writes one 16B
// chunk; a full wave covers a contiguous 1KB of Wf (permuted within).
__global__ __launch_bounds__(256) void kan_prep(
    const float* __restrict__ values, const float* __restrict__ skip_w,
    unsigned short* __restrict__ Wf) {
  const int tid = blockIdx.x * 256 + threadIdx.x;   // 139264 total
  const int q  = tid & 3;
  const int n  = (tid >> 2) & 15;
  const int og = (tid >> 6) & 15;
  const int kb = tid >> 10;
  const int o  = og * 16 + n;
  const int k0 = kb * 32 + q * 8;
  const float* src = (kb < KKNOT / 32)
      ? values + (size_t)o * KKNOT + k0
      : skip_w + (size_t)o * Din + (k0 - KKNOT);
  const float4 v0 = *(const float4*)src;
  const float4 v1 = *(const float4*)(src + 4);
  const size_t chunk = (size_t)kb * 1024 + og * 64 + q * 16 + n;
  *(uint4*)(Wf + chunk * 8) = make_uint4(
      f2bf(v0.x) | (f2bf(v0.y) << 16), f2bf(v0.z) | (f2bf(v0.w) << 16),
      f2bf(v1.x) | (f2bf(v1.y) << 16), f2bf(v1.z) | (f2bf(v1.w) << 16));
}

// --- GEMM: 256 blocks x 256 thr; each wave owns a 64x64 tile for one ks. ---
// Block bl: waves share (mi, ni), take 4 consecutive ks values.
__global__ __launch_bounds__(256) void kan_gemm(
    const float* __restrict__ x, const unsigned short* __restrict__ Wf,
    float* __restrict__ part) {
  const int tid  = threadIdx.x;
  const int wave = tid >> 6, lane = tid & 63;
  const int gw   = blockIdx.x * 4 + wave;        // 0..1023
  const int ks   = gw & 7;
  const int ni   = (gw >> 3) & 3;
  const int mi   = gw >> 5;                      // 0..31
  const int m0   = mi * 64;
  const int og0  = ni * 4;                       // 4 o-groups of 16 = 64 cols
  const int kb0  = ks * SPS, kb1 = kb0 + SPS;

  const int lrow = lane & 15, lq = lane >> 4;
  const int dsel = lq >> 1;                      // which of the 2 dims in a kblock
  const float hbase = (float)((lq & 1) * 8);     // hat index base for this quad

  const uint4* B = (const uint4*)Wf;             // chunk = kb*1024 + og*64 + lane

  floatx4 acc[4][4] = {};
  uint4 bb[2][4];
  float xs[2][4];

  // Prolog: prefetch kb0.
  #pragma unroll
  for (int j = 0; j < 4; ++j) bb[0][j] = B[(size_t)kb0 * 1024 + (og0 + j) * 64 + lane];
  if (kb0 < KKNOT / 32) {
    #pragma unroll
    for (int i = 0; i < 4; ++i)
      xs[0][i] = x[(size_t)(m0 + 16 * i + lrow) * Din + kb0 * 2 + dsel];
  }

  for (int s = 0; s < SPS; ++s) {
    const int kb = kb0 + s;
    const int cur = s & 1, nxt = cur ^ 1;

    // Prefetch next kblock (B-frags + knot x). Waited one iteration later.
    if (s + 1 < SPS) {
      const int kn = kb + 1;
      #pragma unroll
      for (int j = 0; j < 4; ++j) bb[nxt][j] = B[(size_t)kn * 1024 + (og0 + j) * 64 + lane];
      if (kn < KKNOT / 32) {
        #pragma unroll
        for (int i = 0; i < 4; ++i)
          xs[nxt][i] = x[(size_t)(m0 + 16 * i + lrow) * Din + kn * 2 + dsel];
      }
    }

    // Build 4 A-frags (one per 16-row m-tile) in registers.
    shortx8 af[4];
    if (kb < KKNOT / 32) {                       // knot region: hat weights
      #pragma unroll
      for (int i = 0; i < 4; ++i) {
        const float t = (clamp1(xs[cur][i]) + 1.f) * INV_H;
        FragCvt c;
        unsigned int uu[4];
        #pragma unroll
        for (int p = 0; p < 4; ++p) {
          const float e0 = fmaxf(0.f, 1.f - fabsf(t - (hbase + (float)(2 * p))));
          const float e1 = fmaxf(0.f, 1.f - fabsf(t - (hbase + (float)(2 * p + 1))));
          uu[p] = f2bf(e0) | (f2bf(e1) << 16);
        }
        c.u = make_uint4(uu[0], uu[1], uu[2], uu[3]);
        af[i] = c.s;
      }
    } else {                                     // skip region: clamp(x) cols
      const int xoff = (kb - KKNOT / 32) * 32 + lq * 8;
      #pragma unroll
      for (int i = 0; i < 4; ++i) {
        const float* xp = x + (size_t)(m0 + 16 * i + lrow) * Din + xoff;
        const float4 v0 = *(const float4*)xp;
        const float4 v1 = *(const float4*)(xp + 4);
        FragCvt c;
        c.u = make_uint4(
            f2bf(clamp1(v0.x)) | (f2bf(clamp1(v0.y)) << 16),
            f2bf(clamp1(v0.z)) | (f2bf(clamp1(v0.w)) << 16),
            f2bf(clamp1(v1.x)) | (f2bf(clamp1(v1.y)) << 16),
            f2bf(clamp1(v1.z)) | (f2bf(clamp1(v1.w)) << 16));
        af[i] = c.s;
      }
    }

    // 16 MFMA on the current B-frags.
    #pragma unroll
    for (int j = 0; j < 4; ++j) {
      FragCvt bc; bc.u = bb[cur][j];
      const shortx8 bf = bc.s;
      #pragma unroll
      for (int i = 0; i < 4; ++i)
        acc[i][j] = __builtin_amdgcn_mfma_f32_16x16x32_bf16(af[i], bf, acc[i][j], 0, 0, 0);
    }
  }

  // Epilogue: store 64x64 fp32 tile to this split's partial buffer.
  // C/D layout: col = lane&15, row = quad*4 + reg.
  float* P = part + (size_t)ks * Bsz * Dout;
  #pragma unroll
  for (int i = 0; i < 4; ++i) {
    const int grow = m0 + 16 * i + lq * 4;
    #pragma unroll
    for (int j = 0; j < 4; ++j) {
      const int gcol = og0 * 16 + 16 * j + lrow;
      #pragma unroll
      for (int r = 0; r < 4; ++r)
        P[(size_t)(grow + r) * Dout + gcol] = acc[i][j][r];
    }
  }
}

// --- Reduce 8 partials + bias -> out. float4 per thread. ---
__global__ __launch_bounds__(256) void kan_reduce(
    const float* __restrict__ part, const float* __restrict__ skip_b,
    float* __restrict__ out) {
  const int i = blockIdx.x * 256 + threadIdx.x;
  const int base = i * 4;
  const int o = base & (Dout - 1);
  float4 a = *(const float4*)(skip_b + o);
  #pragma unroll
  for (int s = 0; s < NSPLIT; ++s) {
    const float4 p = *(const float4*)(part + (size_t)s * Bsz * Dout + base);
    a.x += p.x; a.y += p.y; a.z += p.z; a.w += p.w;
  }
  *(float4*)(out + base) = a;
}

// ---------------- Fallback (round-1 structure, needs 4.4 MB ws) ----------------
__device__ __forceinline__ void knot_interp(float xraw, float& xv, float& w, int& l) {
  xv = fminf(1.0f, fmaxf(-1.0f, xraw));
  float t = (xv + 1.0f) * INV_H;
  l = (int)ceilf(t) - 1;
  l = l < 0 ? 0 : (l > Kn - 2 ? Kn - 2 : l);
  float g0 = -1.0f + Hgrid * (float)l;
  w = (xv - g0) * INV_H;
}

__global__ __launch_bounds__(256) void prep_transpose(
    const float* __restrict__ values, const float* __restrict__ skip_w,
    float* __restrict__ vt, float* __restrict__ swt) {
  int idx = blockIdx.x * blockDim.x + threadIdx.x;
  if (idx < Din * Kn * Dout) {
    int k = idx & (Kn - 1);
    int d = (idx >> 4) & (Din - 1);
    int o = idx >> 12;
    vt[(d * Kn + k) * Dout + o] = values[idx];
  }
  if (idx < Dout * Din) {
    int d = idx & (Din - 1);
    int o = idx >> 8;
    swt[d * Dout + o] = skip_w[idx];
  }
}

__global__ __launch_bounds__(256) void kan_main(
    const float* __restrict__ x, const float* __restrict__ vt,
    const float* __restrict__ swt, const float* __restrict__ skip_b,
    float* __restrict__ out) {
  __shared__ float s_w[4][Din];
  __shared__ float s_x[4][Din];
  __shared__ int   s_l[4][Din];
  const int tid = threadIdx.x;
  const int b0  = blockIdx.x * 4;
  for (int i = tid; i < 4 * Din; i += 256) {
    int bb = i >> 8;
    int d  = i & (Din - 1);
    float xv, w; int l;
    knot_interp(x[(b0 + bb) * Din + d], xv, w, l);
    s_w[bb][d] = w; s_x[bb][d] = xv; s_l[bb][d] = l;
  }
  __syncthreads();
  const int g = tid >> 6, lane = tid & 63;
  const int o = lane << 2, b = b0 + g;
  float4 acc = make_float4(0.f, 0.f, 0.f, 0.f);
  for (int d = 0; d < Din; ++d) {
    const float w = s_w[g][d], xv = s_x[g][d];
    const int l = s_l[g][d];
    const float* base = vt + (d * Kn + l) * Dout + o;
    const float4 vl = *(const float4*)(base);
    const float4 vr = *(const float4*)(base + Dout);
    const float4 sw = *(const float4*)(swt + d * Dout + o);
    acc.x = fmaf(xv, sw.x, fmaf(w, vr.x - vl.x, acc.x + vl.x));
    acc.y = fmaf(xv, sw.y, fmaf(w, vr.y - vl.y, acc.y + vl.y));
    acc.z = fmaf(xv, sw.z, fmaf(w, vr.z - vl.z, acc.z + vl.z));
    acc.w = fmaf(xv, sw.w, fmaf(w, vr.w - vl.w, acc.w + vl.w));
  }
  const float4 bias = *(const float4*)(skip_b + o);
  acc.x += bias.x; acc.y += bias.y; acc.z += bias.z; acc.w += bias.w;
  *(float4*)(out + (size_t)b * Dout + o) = acc;
}

extern "C" void kernel_launch(void* const* d_in, const int* in_sizes, int n_in,
                              void* d_out, int out_size, void* d_ws, size_t ws_size,
                              hipStream_t stream) {
  (void)in_sizes; (void)n_in; (void)out_size;
  const float* x      = (const float*)d_in[0];
  const float* values = (const float*)d_in[1];
  const float* skip_w = (const float*)d_in[2];
  const float* skip_b = (const float*)d_in[3];
  float* out = (float*)d_out;

  const size_t wf_bytes   = (size_t)Dout * Ksp * sizeof(unsigned short);   // 2.23 MB
  const size_t part_bytes = (size_t)NSPLIT * Bsz * Dout * sizeof(float);   // 16.8 MB
  const size_t need_gemm  = wf_bytes + part_bytes;
  const size_t need_fb    = (size_t)(Din * Kn * Dout + Din * Dout) * sizeof(float);

  if (ws_size >= need_gemm) {
    unsigned short* Wf = (unsigned short*)d_ws;
    float* part = (float*)((char*)d_ws + wf_bytes);
    kan_prep<<<(KB * 1024) / 256, 256, 0, stream>>>(values, skip_w, Wf);
    kan_gemm<<<256, 256, 0, stream>>>(x, Wf, part);
    kan_reduce<<<Bsz * Dout / 4 / 256, 256, 0, stream>>>(part, skip_b, out);
  } else if (ws_size >= need_fb) {
    float* vt  = (float*)d_ws;
    float* swt = vt + Din * Kn * Dout;
    prep_transpose<<<(Din * Kn * Dout + 255) / 256, 256, 0, stream>>>(values, skip_w, vt, swt);
    kan_main<<<Bsz / 4, 256, 0, stream>>>(x, vt, swt, skip_b, out);
  }
}

// Round 7
// 90.426 us; speedup vs baseline: 1.2315x; 1.1301x over previous
//
#include <hip/hip_runtime.h>
#include <hip/hip_bf16.h>

// KANLinear as fragment-direct bf16 MFMA GEMM (no per-step barriers):
//   y = A @ W'^T + skip_b
//   A (2048 x 4352) VIRTUAL: per dim d, 16 hat weights max(0,1-|t-k|),
//     t=(clamp(x)+1)*7.5 (cols 0..4095), then 256 cols clamp(x) (skip).
//   W' (256 x 4352) bf16, PRE-PERMUTED into MFMA B-fragment order (Wf):
//     chunk(kb,og,q,n) = W'[og*16+n][kb*32+q*8 .. +8]; a wave loads a 16x32
//     B-frag as one coalesced global_load_dwordx4 (lane = q*16+n).
// Block = 4 waves sharing (mi,ks); x slice staged once in LDS (4KB);
// NSPLIT=17 split-K -> fp32 partials -> reduce(+bias).

namespace {
constexpr int Bsz  = 2048;
constexpr int Din  = 256;
constexpr int Dout = 256;
constexpr int Kn   = 16;
constexpr int KKNOT = Din * Kn;        // 4096
constexpr int Ksp   = KKNOT + Din;     // 4352
constexpr int KB    = Ksp / 32;        // 136 k-blocks of 32
constexpr int KBK   = KKNOT / 32;      // 128 knot k-blocks
constexpr float INV_H = 7.5f;          // 1 / (2/15)
constexpr float Hgrid = 2.0f / 15.0f;

constexpr int NSPLIT = 17;             // 16 knot splits (8 kb) + 1 skip split (8 kb)
constexpr int SPS    = 8;              // kblocks per split
constexpr int MT     = Bsz / 64;       // 32
}

typedef __attribute__((ext_vector_type(8))) short shortx8;   // 8 bf16 = 4 VGPR
typedef __attribute__((ext_vector_type(4))) float floatx4;   // MFMA acc

__device__ __forceinline__ unsigned int f2bf(float f) {
  __hip_bfloat16 h = __float2bfloat16(f);
  return (unsigned int)*reinterpret_cast<unsigned short*>(&h);
}
__device__ __forceinline__ float clamp1(float v) {
  return fminf(1.f, fmaxf(-1.f, v));
}

union FragCvt { uint4 u; shortx8 s; };

// --- Prep: permute W' into B-fragment order. 544 blocks x 256. ---
__global__ __launch_bounds__(256) void kan_prep(
    const float* __restrict__ values, const float* __restrict__ skip_w,
    unsigned short* __restrict__ Wf) {
  const int tid = blockIdx.x * 256 + threadIdx.x;   // 139264 total
  const int q  = tid & 3;
  const int n  = (tid >> 2) & 15;
  const int og = (tid >> 6) & 15;
  const int kb = tid >> 10;
  const int o  = og * 16 + n;
  const int k0 = kb * 32 + q * 8;
  const float* src = (kb < KBK)
      ? values + (size_t)o * KKNOT + k0
      : skip_w + (size_t)o * Din + (k0 - KKNOT);
  const float4 v0 = *(const float4*)src;
  const float4 v1 = *(const float4*)(src + 4);
  const size_t chunk = (size_t)kb * 1024 + og * 64 + q * 16 + n;
  *(uint4*)(Wf + chunk * 8) = make_uint4(
      f2bf(v0.x) | (f2bf(v0.y) << 16), f2bf(v0.z) | (f2bf(v0.w) << 16),
      f2bf(v1.x) | (f2bf(v1.y) << 16), f2bf(v1.z) | (f2bf(v1.w) << 16));
}

// --- GEMM: grid = 32 mi x 17 ks = 544 blocks, 256 thr (4 waves = 4 ni). ---
__global__ __launch_bounds__(256) void kan_gemm(
    const float* __restrict__ x, const unsigned short* __restrict__ Wf,
    float* __restrict__ part) {
  __shared__ float sx[16 * 64];                  // [d_local][row], 4 KB

  const int tid  = threadIdx.x;
  const int wave = tid >> 6, lane = tid & 63;
  const int ks   = blockIdx.x % NSPLIT;
  const int mi   = blockIdx.x / NSPLIT;
  const int m0   = mi * 64;
  const int ni   = wave;
  const int og0  = ni * 4;                       // 4 o-groups of 16 = 64 cols
  const int kb0  = (ks < 16) ? ks * SPS : KBK;   // skip split starts at kb=128

  const int lrow = lane & 15, lq = lane >> 4;
  const int dsel  = lq >> 1;                     // which of 2 dims in a kblock
  const float hbase = (float)((lq & 1) * 8);     // hat index base for this quad

  const uint4* B = (const uint4*)Wf;             // chunk = kb*1024 + og*64 + lane

  floatx4 acc[4][4] = {};
  uint4 bb[2][4];

  if (ks < 16) {
    // ---- Stage x slice: rows m0..m0+63, dims d0..d0+15 -> sx[d][row]. ----
    {
      const int row = tid >> 2, dq = tid & 3;
      const float4 v = *(const float4*)(x + (size_t)(m0 + row) * Din + ks * 16 + 4 * dq);
      sx[(4 * dq + 0) * 64 + row] = v.x;
      sx[(4 * dq + 1) * 64 + row] = v.y;
      sx[(4 * dq + 2) * 64 + row] = v.z;
      sx[(4 * dq + 3) * 64 + row] = v.w;
    }
    __syncthreads();

    // Prolog: prefetch kb0's B-frags.
    #pragma unroll
    for (int j = 0; j < 4; ++j)
      bb[0][j] = B[(size_t)kb0 * 1024 + (og0 + j) * 64 + lane];

    for (int s = 0; s < SPS; ++s) {
      const int cur = s & 1, nxt = cur ^ 1;
      if (s + 1 < SPS) {
        #pragma unroll
        for (int j = 0; j < 4; ++j)
          bb[nxt][j] = B[(size_t)(kb0 + s + 1) * 1024 + (og0 + j) * 64 + lane];
      }
      const int dloc = 2 * s + dsel;
      // Build 4 A-frags from LDS x (broadcast reads, 2-way bank alias = free).
      shortx8 af[4];
      #pragma unroll
      for (int i = 0; i < 4; ++i) {
        const float xv = sx[dloc * 64 + 16 * i + lrow];
        const float t = (clamp1(xv) + 1.f) * INV_H;
        unsigned int uu[4];
        #pragma unroll
        for (int p = 0; p < 4; ++p) {
          const float e0 = fmaxf(0.f, 1.f - fabsf(t - (hbase + (float)(2 * p))));
          const float e1 = fmaxf(0.f, 1.f - fabsf(t - (hbase + (float)(2 * p + 1))));
          uu[p] = f2bf(e0) | (f2bf(e1) << 16);
        }
        FragCvt c; c.u = make_uint4(uu[0], uu[1], uu[2], uu[3]);
        af[i] = c.s;
      }
      #pragma unroll
      for (int j = 0; j < 4; ++j) {
        FragCvt bc; bc.u = bb[cur][j];
        #pragma unroll
        for (int i = 0; i < 4; ++i)
          acc[i][j] = __builtin_amdgcn_mfma_f32_16x16x32_bf16(af[i], bc.s, acc[i][j], 0, 0, 0);
      }
    }
  } else {
    // ---- Skip split: A cols are clamp(x); direct float4 loads (R6 path). ----
    #pragma unroll
    for (int j = 0; j < 4; ++j)
      bb[0][j] = B[(size_t)kb0 * 1024 + (og0 + j) * 64 + lane];

    for (int s = 0; s < SPS; ++s) {
      const int kb = kb0 + s;
      const int cur = s & 1, nxt = cur ^ 1;
      if (s + 1 < SPS) {
        #pragma unroll
        for (int j = 0; j < 4; ++j)
          bb[nxt][j] = B[(size_t)(kb + 1) * 1024 + (og0 + j) * 64 + lane];
      }
      const int xoff = (kb - KBK) * 32 + lq * 8;
      shortx8 af[4];
      #pragma unroll
      for (int i = 0; i < 4; ++i) {
        const float* xp = x + (size_t)(m0 + 16 * i + lrow) * Din + xoff;
        const float4 v0 = *(const float4*)xp;
        const float4 v1 = *(const float4*)(xp + 4);
        FragCvt c;
        c.u = make_uint4(
            f2bf(clamp1(v0.x)) | (f2bf(clamp1(v0.y)) << 16),
            f2bf(clamp1(v0.z)) | (f2bf(clamp1(v0.w)) << 16),
            f2bf(clamp1(v1.x)) | (f2bf(clamp1(v1.y)) << 16),
            f2bf(clamp1(v1.z)) | (f2bf(clamp1(v1.w)) << 16));
        af[i] = c.s;
      }
      #pragma unroll
      for (int j = 0; j < 4; ++j) {
        FragCvt bc; bc.u = bb[cur][j];
        #pragma unroll
        for (int i = 0; i < 4; ++i)
          acc[i][j] = __builtin_amdgcn_mfma_f32_16x16x32_bf16(af[i], bc.s, acc[i][j], 0, 0, 0);
      }
    }
  }

  // Epilogue: store 64x64 fp32 tile to this split's partial buffer.
  // C/D layout: col = lane&15, row = quad*4 + reg.
  float* P = part + (size_t)ks * Bsz * Dout;
  #pragma unroll
  for (int i = 0; i < 4; ++i) {
    const int grow = m0 + 16 * i + lq * 4;
    #pragma unroll
    for (int j = 0; j < 4; ++j) {
      const int gcol = og0 * 16 + 16 * j + lrow;
      #pragma unroll
      for (int r = 0; r < 4; ++r)
        P[(size_t)(grow + r) * Dout + gcol] = acc[i][j][r];
    }
  }
}

// --- Reduce 17 partials + bias -> out. float4 per thread. ---
__global__ __launch_bounds__(256) void kan_reduce(
    const float* __restrict__ part, const float* __restrict__ skip_b,
    float* __restrict__ out) {
  const int i = blockIdx.x * 256 + threadIdx.x;
  const int base = i * 4;
  const int o = base & (Dout - 1);
  float4 a = *(const float4*)(skip_b + o);
  #pragma unroll
  for (int s = 0; s < NSPLIT; ++s) {
    const float4 p = *(const float4*)(part + (size_t)s * Bsz * Dout + base);
    a.x += p.x; a.y += p.y; a.z += p.z; a.w += p.w;
  }
  *(float4*)(out + base) = a;
}

// ---------------- Fallback (round-1 structure, needs 4.4 MB ws) ----------------
__device__ __forceinline__ void knot_interp(float xraw, float& xv, float& w, int& l) {
  xv = fminf(1.0f, fmaxf(-1.0f, xraw));
  float t = (xv + 1.0f) * INV_H;
  l = (int)ceilf(t) - 1;
  l = l < 0 ? 0 : (l > Kn - 2 ? Kn - 2 : l);
  float g0 = -1.0f + Hgrid * (float)l;
  w = (xv - g0) * INV_H;
}

__global__ __launch_bounds__(256) void prep_transpose(
    const float* __restrict__ values, const float* __restrict__ skip_w,
    float* __restrict__ vt, float* __restrict__ swt) {
  int idx = blockIdx.x * blockDim.x + threadIdx.x;
  if (idx < Din * Kn * Dout) {
    int k = idx & (Kn - 1);
    int d = (idx >> 4) & (Din - 1);
    int o = idx >> 12;
    vt[(d * Kn + k) * Dout + o] = values[idx];
  }
  if (idx < Dout * Din) {
    int d = idx & (Din - 1);
    int o = idx >> 8;
    swt[d * Dout + o] = skip_w[idx];
  }
}

__global__ __launch_bounds__(256) void kan_main(
    const float* __restrict__ x, const float* __restrict__ vt,
    const float* __restrict__ swt, const float* __restrict__ skip_b,
    float* __restrict__ out) {
  __shared__ float s_w[4][Din];
  __shared__ float s_x[4][Din];
  __shared__ int   s_l[4][Din];
  const int tid = threadIdx.x;
  const int b0  = blockIdx.x * 4;
  for (int i = tid; i < 4 * Din; i += 256) {
    int bb = i >> 8;
    int d  = i & (Din - 1);
    float xv, w; int l;
    knot_interp(x[(b0 + bb) * Din + d], xv, w, l);
    s_w[bb][d] = w; s_x[bb][d] = xv; s_l[bb][d] = l;
  }
  __syncthreads();
  const int g = tid >> 6, lane = tid & 63;
  const int o = lane << 2, b = b0 + g;
  float4 acc = make_float4(0.f, 0.f, 0.f, 0.f);
  for (int d = 0; d < Din; ++d) {
    const float w = s_w[g][d], xv = s_x[g][d];
    const int l = s_l[g][d];
    const float* base = vt + (d * Kn + l) * Dout + o;
    const float4 vl = *(const float4*)(base);
    const float4 vr = *(const float4*)(base + Dout);
    const float4 sw = *(const float4*)(swt + d * Dout + o);
    acc.x = fmaf(xv, sw.x, fmaf(w, vr.x - vl.x, acc.x + vl.x));
    acc.y = fmaf(xv, sw.y, fmaf(w, vr.y - vl.y, acc.y + vl.y));
    acc.z = fmaf(xv, sw.z, fmaf(w, vr.z - vl.z, acc.z + vl.z));
    acc.w = fmaf(xv, sw.w, fmaf(w, vr.w - vl.w, acc.w + vl.w));
  }
  const float4 bias = *(const float4*)(skip_b + o);
  acc.x += bias.x; acc.y += bias.y; acc.z += bias.z; acc.w += bias.w;
  *(float4*)(out + (size_t)b * Dout + o) = acc;
}

extern "C" void kernel_launch(void* const* d_in, const int* in_sizes, int n_in,
                              void* d_out, int out_size, void* d_ws, size_t ws_size,
                              hipStream_t stream) {
  (void)in_sizes; (void)n_in; (void)out_size;
  const float* x      = (const float*)d_in[0];
  const float* values = (const float*)d_in[1];
  const float* skip_w = (const float*)d_in[2];
  const float* skip_b = (const float*)d_in[3];
  float* out = (float*)d_out;

  const size_t wf_bytes   = (size_t)Dout * Ksp * sizeof(unsigned short);   // 2.23 MB
  const size_t part_bytes = (size_t)NSPLIT * Bsz * Dout * sizeof(float);   // 35.7 MB
  const size_t need_gemm  = wf_bytes + part_bytes;
  const size_t need_fb    = (size_t)(Din * Kn * Dout + Din * Dout) * sizeof(float);

  if (ws_size >= need_gemm) {
    unsigned short* Wf = (unsigned short*)d_ws;
    float* part = (float*)((char*)d_ws + wf_bytes);
    kan_prep<<<(KB * 1024) / 256, 256, 0, stream>>>(values, skip_w, Wf);
    kan_gemm<<<MT * NSPLIT, 256, 0, stream>>>(x, Wf, part);
    kan_reduce<<<Bsz * Dout / 4 / 256, 256, 0, stream>>>(part, skip_b, out);
  } else if (ws_size >= need_fb) {
    float* vt  = (float*)d_ws;
    float* swt = vt + Din * Kn * Dout;
    prep_transpose<<<(Din * Kn * Dout + 255) / 256, 256, 0, stream>>>(values, skip_w, vt, swt);
    kan_main<<<Bsz / 4, 256, 0, stream>>>(x, vt, swt, skip_b, out);
  }
}

// Round 8
// 81.213 us; speedup vs baseline: 1.3712x; 1.1134x over previous
//
#include <hip/hip_runtime.h>
#include <hip/hip_bf16.h>

// KANLinear as fragment-direct bf16 MFMA GEMM:
//   y = A @ W'^T + skip_b
//   A (2048 x 4352) VIRTUAL: per dim d, 16 hat weights max(0,1-|t-k|),
//     t=(clamp(x)+1)*7.5 (cols 0..4095), then 256 cols clamp(x) (skip).
//     A-fragment tiles are built cooperatively in LDS (once per block-step,
//     shared by all 4 waves), double-buffered, 1 barrier/step.
//   W' (256 x 4352) bf16, PRE-PERMUTED into MFMA B-fragment order (Wf):
//     chunk(kb,og,q,n) = W'[og*16+n][kb*32+q*8 .. +8]; a wave loads a 16x32
//     B-frag as one coalesced global_load_dwordx4 (lane = q*16+n).
// NSPLIT=17 split-K -> fp32 partials in TILE-BLOCKED layout (1KB-coalesced
// epilogue stores, zero write amplification) -> reduce(+bias).

namespace {
constexpr int Bsz  = 2048;
constexpr int Din  = 256;
constexpr int Dout = 256;
constexpr int Kn   = 16;
constexpr int KKNOT = Din * Kn;        // 4096
constexpr int Ksp   = KKNOT + Din;     // 4352
constexpr int KB    = Ksp / 32;        // 136 k-blocks of 32
constexpr int KBK   = KKNOT / 32;      // 128 knot k-blocks
constexpr float INV_H = 7.5f;          // 1 / (2/15)
constexpr float Hgrid = 2.0f / 15.0f;

constexpr int NSPLIT = 17;             // 16 knot splits + 1 skip split (8 kb each)
constexpr int SPS    = 8;              // kblocks per split
constexpr int MT     = Bsz / 64;       // 32
constexpr int TILE_F = 64 * 64;        // floats per wave tile (4096)
constexpr int PELEM  = Bsz * Dout;     // 524288 floats per split partial
}

typedef __attribute__((ext_vector_type(8))) short shortx8;   // 8 bf16 = 4 VGPR
typedef __attribute__((ext_vector_type(4))) float floatx4;   // MFMA acc

__device__ __forceinline__ unsigned int f2bf(float f) {
  __hip_bfloat16 h = __float2bfloat16(f);
  return (unsigned int)*reinterpret_cast<unsigned short*>(&h);
}
__device__ __forceinline__ float clamp1(float v) {
  return fminf(1.f, fmaxf(-1.f, v));
}
// Pack two pre-rounded f32 bit patterns (already +0x8000) into bf16x2.
__device__ __forceinline__ unsigned int packbf(unsigned int e0, unsigned int e1) {
  return (e1 & 0xffff0000u) | (e0 >> 16);
}
__device__ __forceinline__ unsigned int rnd(float f) {
  return __float_as_uint(f) + 0x8000u;
}

// --- Prep: permute W' into B-fragment order. 544 blocks x 256. ---
__global__ __launch_bounds__(256) void kan_prep(
    const float* __restrict__ values, const float* __restrict__ skip_w,
    unsigned short* __restrict__ Wf) {
  const int tid = blockIdx.x * 256 + threadIdx.x;   // 139264 total
  const int q  = tid & 3;
  const int n  = (tid >> 2) & 15;
  const int og = (tid >> 6) & 15;
  const int kb = tid >> 10;
  const int o  = og * 16 + n;
  const int k0 = kb * 32 + q * 8;
  const float* src = (kb < KBK)
      ? values + (size_t)o * KKNOT + k0
      : skip_w + (size_t)o * Din + (k0 - KKNOT);
  const float4 v0 = *(const float4*)src;
  const float4 v1 = *(const float4*)(src + 4);
  const size_t chunk = (size_t)kb * 1024 + og * 64 + q * 16 + n;
  *(uint4*)(Wf + chunk * 8) = make_uint4(
      f2bf(v0.x) | (f2bf(v0.y) << 16), f2bf(v0.z) | (f2bf(v0.w) << 16),
      f2bf(v1.x) | (f2bf(v1.y) << 16), f2bf(v1.z) | (f2bf(v1.w) << 16));
}

// --- GEMM: grid = 32 mi x 17 ks = 544 blocks, 256 thr (4 waves = 4 ni). ---
__global__ __launch_bounds__(256) void kan_gemm(
    const float* __restrict__ x, const unsigned short* __restrict__ Wf,
    float* __restrict__ part) {
  __shared__ float sx[16 * 64];                            // [dloc][row], 4 KB
  __shared__ __align__(16) unsigned short aLds[2][64 * 32]; // A-frag tiles, 2x4 KB

  const int tid  = threadIdx.x;
  const int wave = tid >> 6, lane = tid & 63;
  const int ks   = blockIdx.x % NSPLIT;
  const int mi   = blockIdx.x / NSPLIT;
  const int m0   = mi * 64;
  const int og0  = wave * 4;                     // this wave's 64 out-cols
  const int kb0  = (ks < 16) ? ks * SPS : KBK;

  const int lrow = lane & 15, lq = lane >> 4;

  // Build mappings (256 threads cover the 64x32 A tile; 16B chunk each).
  const int brow_k = tid & 63, bseg_k = tid >> 6;   // knot: (row, seg)
  const int brow_s = tid >> 2, bseg_s = tid & 3;    // skip: (row, seg)

  const uint4* B = (const uint4*)Wf;             // chunk = kb*1024 + og*64 + lane

  floatx4 acc[4][4] = {};
  uint4 bb[2][4];

  if (ks < 16) {
    // Stage x slice: rows m0..m0+63, dims ks*16..+15 -> sx[dloc][row].
    const int row = tid >> 2, dq = tid & 3;
    const float4 v = *(const float4*)(x + (size_t)(m0 + row) * Din + ks * 16 + 4 * dq);
    sx[(4 * dq + 0) * 64 + row] = v.x;
    sx[(4 * dq + 1) * 64 + row] = v.y;
    sx[(4 * dq + 2) * 64 + row] = v.z;
    sx[(4 * dq + 3) * 64 + row] = v.w;
    __syncthreads();
  }

  // Prolog: prefetch kb0's B-frags.
  #pragma unroll
  for (int j = 0; j < 4; ++j)
    bb[0][j] = B[(size_t)kb0 * 1024 + (og0 + j) * 64 + lane];

  for (int s = 0; s < SPS; ++s) {
    const int cur = s & 1;
    // Prefetch next B-frags (waited next iteration).
    if (s + 1 < SPS) {
      #pragma unroll
      for (int j = 0; j < 4; ++j)
        bb[cur ^ 1][j] = B[(size_t)(kb0 + s + 1) * 1024 + (og0 + j) * 64 + lane];
    }

    // Cooperative A-tile build into aLds[cur] (each thread: one 16B chunk).
    if (ks < 16) {
      const int dloc = 2 * s + (bseg_k >> 1);
      const float xv = sx[dloc * 64 + brow_k];
      const float t  = (clamp1(xv) + 1.f) * INV_H;
      const float h0 = (float)((bseg_k & 1) * 8);
      unsigned int e[8];
      #pragma unroll
      for (int h = 0; h < 8; ++h)
        e[h] = rnd(fmaxf(0.f, 1.f - fabsf(t - (h0 + (float)h))));
      *(uint4*)((char*)&aLds[cur][0] + brow_k * 64 + bseg_k * 16) =
          make_uint4(packbf(e[0], e[1]), packbf(e[2], e[3]),
                     packbf(e[4], e[5]), packbf(e[6], e[7]));
    } else {
      const float* xp = x + (size_t)(m0 + brow_s) * Din + (kb0 + s - KBK) * 32 + bseg_s * 8;
      const float4 v0 = *(const float4*)xp;
      const float4 v1 = *(const float4*)(xp + 4);
      unsigned int e[8];
      e[0] = rnd(clamp1(v0.x)); e[1] = rnd(clamp1(v0.y));
      e[2] = rnd(clamp1(v0.z)); e[3] = rnd(clamp1(v0.w));
      e[4] = rnd(clamp1(v1.x)); e[5] = rnd(clamp1(v1.y));
      e[6] = rnd(clamp1(v1.z)); e[7] = rnd(clamp1(v1.w));
      *(uint4*)((char*)&aLds[cur][0] + brow_s * 64 + bseg_s * 16) =
          make_uint4(packbf(e[0], e[1]), packbf(e[2], e[3]),
                     packbf(e[4], e[5]), packbf(e[6], e[7]));
    }
    __syncthreads();   // tile visible; prior-buffer reads done 2 steps back

    // A-frags from LDS (row = 16i+lrow, k-half = lq): ds_read_b128.
    shortx8 af[4];
    #pragma unroll
    for (int i = 0; i < 4; ++i)
      af[i] = *(const shortx8*)((const char*)&aLds[cur][0] + (16 * i + lrow) * 64 + lq * 16);

    #pragma unroll
    for (int j = 0; j < 4; ++j) {
      union { uint4 u; shortx8 s; } bc;
      bc.u = bb[cur][j];
      #pragma unroll
      for (int i = 0; i < 4; ++i)
        acc[i][j] = __builtin_amdgcn_mfma_f32_16x16x32_bf16(af[i], bc.s, acc[i][j], 0, 0, 0);
    }
  }

  // Epilogue: tile-blocked partial layout -> every store = 1KB coalesced.
  // P[ks][tile = mi*4+wave][ ((i*4+j)*64 + lane)*4 + r ]
  float* P = part + (size_t)ks * PELEM + (size_t)(mi * 4 + wave) * TILE_F;
  #pragma unroll
  for (int i = 0; i < 4; ++i)
    #pragma unroll
    for (int j = 0; j < 4; ++j)
      *(floatx4*)&P[((i * 4 + j) * 64 + lane) * 4] = acc[i][j];
}

// --- Reduce 17 tile-blocked partials + bias -> out. 512 blocks x 256. ---
__global__ __launch_bounds__(256) void kan_reduce(
    const float* __restrict__ part, const float* __restrict__ skip_b,
    float* __restrict__ out) {
  const int tid = blockIdx.x * 256 + threadIdx.x;   // float4 index, 131072 total
  float4 a = make_float4(0.f, 0.f, 0.f, 0.f);
  #pragma unroll
  for (int s = 0; s < NSPLIT; ++s) {
    const float4 p = *(const float4*)(part + (size_t)s * PELEM + (size_t)tid * 4);
    a.x += p.x; a.y += p.y; a.z += p.z; a.w += p.w;
  }
  // Decode tile-blocked layout back to (b, o).
  const int f4   = tid & 1023, tile = tid >> 10;
  const int ij   = f4 >> 6,   lane = f4 & 63;
  const int i    = ij >> 2,   j    = ij & 3;
  const int mi   = tile >> 2, ni   = tile & 3;
  const int b0   = mi * 64 + 16 * i + (lane >> 4) * 4;
  const int o    = ni * 64 + 16 * j + (lane & 15);
  const float sb = skip_b[o];
  out[(size_t)(b0 + 0) * Dout + o] = a.x + sb;
  out[(size_t)(b0 + 1) * Dout + o] = a.y + sb;
  out[(size_t)(b0 + 2) * Dout + o] = a.z + sb;
  out[(size_t)(b0 + 3) * Dout + o] = a.w + sb;
}

// ---------------- Fallback (round-1 structure, needs 4.4 MB ws) ----------------
__device__ __forceinline__ void knot_interp(float xraw, float& xv, float& w, int& l) {
  xv = fminf(1.0f, fmaxf(-1.0f, xraw));
  float t = (xv + 1.0f) * INV_H;
  l = (int)ceilf(t) - 1;
  l = l < 0 ? 0 : (l > Kn - 2 ? Kn - 2 : l);
  float g0 = -1.0f + Hgrid * (float)l;
  w = (xv - g0) * INV_H;
}

__global__ __launch_bounds__(256) void prep_transpose(
    const float* __restrict__ values, const float* __restrict__ skip_w,
    float* __restrict__ vt, float* __restrict__ swt) {
  int idx = blockIdx.x * blockDim.x + threadIdx.x;
  if (idx < Din * Kn * Dout) {
    int k = idx & (Kn - 1);
    int d = (idx >> 4) & (Din - 1);
    int o = idx >> 12;
    vt[(d * Kn + k) * Dout + o] = values[idx];
  }
  if (idx < Dout * Din) {
    int d = idx & (Din - 1);
    int o = idx >> 8;
    swt[d * Dout + o] = skip_w[idx];
  }
}

__global__ __launch_bounds__(256) void kan_main(
    const float* __restrict__ x, const float* __restrict__ vt,
    const float* __restrict__ swt, const float* __restrict__ skip_b,
    float* __restrict__ out) {
  __shared__ float s_w[4][Din];
  __shared__ float s_x[4][Din];
  __shared__ int   s_l[4][Din];
  const int tid = threadIdx.x;
  const int b0  = blockIdx.x * 4;
  for (int i = tid; i < 4 * Din; i += 256) {
    int bb = i >> 8;
    int d  = i & (Din - 1);
    float xv, w; int l;
    knot_interp(x[(b0 + bb) * Din + d], xv, w, l);
    s_w[bb][d] = w; s_x[bb][d] = xv; s_l[bb][d] = l;
  }
  __syncthreads();
  const int g = tid >> 6, lane = tid & 63;
  const int o = lane << 2, b = b0 + g;
  float4 acc = make_float4(0.f, 0.f, 0.f, 0.f);
  for (int d = 0; d < Din; ++d) {
    const float w = s_w[g][d], xv = s_x[g][d];
    const int l = s_l[g][d];
    const float* base = vt + (d * Kn + l) * Dout + o;
    const float4 vl = *(const float4*)(base);
    const float4 vr = *(const float4*)(base + Dout);
    const float4 sw = *(const float4*)(swt + d * Dout + o);
    acc.x = fmaf(xv, sw.x, fmaf(w, vr.x - vl.x, acc.x + vl.x));
    acc.y = fmaf(xv, sw.y, fmaf(w, vr.y - vl.y, acc.y + vl.y));
    acc.z = fmaf(xv, sw.z, fmaf(w, vr.z - vl.z, acc.z + vl.z));
    acc.w = fmaf(xv, sw.w, fmaf(w, vr.w - vl.w, acc.w + vl.w));
  }
  const float4 bias = *(const float4*)(skip_b + o);
  acc.x += bias.x; acc.y += bias.y; acc.z += bias.z; acc.w += bias.w;
  *(float4*)(out + (size_t)b * Dout + o) = acc;
}

extern "C" void kernel_launch(void* const* d_in, const int* in_sizes, int n_in,
                              void* d_out, int out_size, void* d_ws, size_t ws_size,
                              hipStream_t stream) {
  (void)in_sizes; (void)n_in; (void)out_size;
  const float* x      = (const float*)d_in[0];
  const float* values = (const float*)d_in[1];
  const float* skip_w = (const float*)d_in[2];
  const float* skip_b = (const float*)d_in[3];
  float* out = (float*)d_out;

  const size_t wf_bytes   = (size_t)Dout * Ksp * sizeof(unsigned short);   // 2.23 MB
  const size_t part_bytes = (size_t)NSPLIT * PELEM * sizeof(float);        // 35.7 MB
  const size_t need_gemm  = wf_bytes + part_bytes;
  const size_t need_fb    = (size_t)(Din * Kn * Dout + Din * Dout) * sizeof(float);

  if (ws_size >= need_gemm) {
    unsigned short* Wf = (unsigned short*)d_ws;
    float* part = (float*)((char*)d_ws + wf_bytes);
    kan_prep<<<(KB * 1024) / 256, 256, 0, stream>>>(values, skip_w, Wf);
    kan_gemm<<<MT * NSPLIT, 256, 0, stream>>>(x, Wf, part);
    kan_reduce<<<PELEM / 4 / 256, 256, 0, stream>>>(part, skip_b, out);
  } else if (ws_size >= need_fb) {
    float* vt  = (float*)d_ws;
    float* swt = vt + Din * Kn * Dout;
    prep_transpose<<<(Din * Kn * Dout + 255) / 256, 256, 0, stream>>>(values, skip_w, vt, swt);
    kan_main<<<Bsz / 4, 256, 0, stream>>>(x, vt, swt, skip_b, out);
  }
}